// Round 1
// baseline (767.993 us; speedup 1.0000x reference)
//
#include <hip/hip_runtime.h>
#include <hip/hip_bf16.h>
#include <math.h>

typedef float float4v __attribute__((ext_vector_type(4)));

constexpr int Bn  = 4;
constexpr int Cc  = 256;    // C_IN
constexpr int Ci  = 128;    // C_INT
constexpr int Nn  = 4096;   // H*W
constexpr size_t Msz = (size_t)Bn * Ci * Nn;   // elements per projected tensor

// ---------------------------------------------------------------------------
// Kernel 1: projections. Stacked rows j in [0,384): theta(0..127) -> K,
// phi(128..255) -> V, g(256..383) -> Q. All stored [b][ch][n] (fp32).
// Grid 768 1-D: L&15 = (b, n-slab) so XCD = L%8 pins slabs -> L2 reuse of x.
// ---------------------------------------------------------------------------
__global__ __launch_bounds__(256)
void proj_kernel(const float* __restrict__ x,
                 const float* __restrict__ tw, const float* __restrict__ tb,
                 const float* __restrict__ pw, const float* __restrict__ pb,
                 const float* __restrict__ gw, const float* __restrict__ gb,
                 float* __restrict__ ws) {
  const int L  = blockIdx.x;
  const int s  = L & 15;
  const int b  = s & 3;
  const int n0 = (s >> 2) << 10;          // 0,1024,2048,3072
  const int j0 = (L >> 4) * 8;            // stacked output row base

  const float* W; const float* bias; float* outb;
  if (j0 < 128)      { W = tw + (size_t)j0*Cc;        bias = tb + j0;
                       outb = ws            + (size_t)b*Ci*Nn + (size_t)j0*Nn; }
  else if (j0 < 256) { W = pw + (size_t)(j0-128)*Cc;  bias = pb + (j0-128);
                       outb = ws + Msz      + (size_t)b*Ci*Nn + (size_t)(j0-128)*Nn; }
  else               { W = gw + (size_t)(j0-256)*Cc;  bias = gb + (j0-256);
                       outb = ws + 2*Msz    + (size_t)b*Ci*Nn + (size_t)(j0-256)*Nn; }

  __shared__ float Wl[Cc][8];             // [c][jj] transposed, 8 KB
  for (int i = threadIdx.x; i < 8*Cc; i += 256) {
    int jj = i >> 8, c = i & 255;
    Wl[c][jj] = W[(size_t)jj*Cc + c];
  }
  __syncthreads();

  const int n = n0 + threadIdx.x * 4;
  const float* xp = x + (size_t)b*Cc*Nn + n;

  float acc[8][4];
  #pragma unroll
  for (int jj = 0; jj < 8; ++jj) {
    float bv = bias[jj];
    #pragma unroll
    for (int k = 0; k < 4; ++k) acc[jj][k] = bv;
  }

  #pragma unroll 4
  for (int c = 0; c < Cc; ++c) {
    float4v xv = *(const float4v*)(xp + (size_t)c*Nn);
    float4v wa = *(const float4v*)&Wl[c][0];
    float4v wb4 = *(const float4v*)&Wl[c][4];
    #pragma unroll
    for (int jj = 0; jj < 4; ++jj)
      #pragma unroll
      for (int k = 0; k < 4; ++k) acc[jj][k]   += wa[jj]  * xv[k];
    #pragma unroll
    for (int jj = 0; jj < 4; ++jj)
      #pragma unroll
      for (int k = 0; k < 4; ++k) acc[jj+4][k] += wb4[jj] * xv[k];
  }

  #pragma unroll
  for (int jj = 0; jj < 8; ++jj) {
    float4v r; 
    #pragma unroll
    for (int k = 0; k < 4; ++k) r[k] = acc[jj][k];
    *(float4v*)(outb + (size_t)jj*Nn + n) = r;
  }
}

// ---------------------------------------------------------------------------
// Kernel 2: flash attention, fp32 VALU.
// Block = 256 thr, 32 rows (r0), m-tiles of 64. Grid 512: b = L&3 so each
// XCD processes one batch -> V+Q (4 MB) fits its L2.
// LDS: K[128][32] 16K | VQ union (V [128][64] / Q^T [64][132]) 33K | P [64][36] 9K
// ---------------------------------------------------------------------------
__global__ __launch_bounds__(256)
void attn_kernel(const float* __restrict__ wsin, float* __restrict__ Sg) {
  const float* Kg = wsin;
  const float* Vg = wsin + Msz;
  const float* Qg = wsin + 2*Msz;

  const int L  = blockIdx.x;
  const int b  = L & 3;
  const int r0 = (L >> 2) * 32;

  __shared__ float Klds[Ci*32];    // [o][r] r-stride 32
  __shared__ float VQ[64*132];     // V: o*64+m ; Q^T: m*132+o
  __shared__ float Pt[64*36];      // [m][r] r-stride 36

  const int tid = threadIdx.x;
  const int rq  = tid >> 5;        // 0..7  : row quad (rows 4rq..4rq+3)
  const int mq  = tid & 31;        // logits: m pair (m = 2mq, 2mq+1)
  const int to  = tid & 31;        // PV    : o quad (o = 4to..4to+3)

  const size_t base = (size_t)b*Ci*Nn;

  for (int i = tid; i < Ci*8; i += 256) {            // 128*32/4
    int o = i >> 3, q = i & 7;
    *(float4v*)&Klds[o*32 + q*4] =
        *(const float4v*)(Kg + base + (size_t)o*Nn + r0 + q*4);
  }

  float acc[4][4] = {};
  float mrow[4], lrow[4];
  #pragma unroll
  for (int i = 0; i < 4; ++i) { mrow[i] = -INFINITY; lrow[i] = 0.0f; }

  for (int mt = 0; mt < Nn/64; ++mt) {
    const int m0 = mt * 64;
    __syncthreads();                                  // prev PV done with VQ
    for (int i = tid; i < Ci*16; i += 256) {          // V tile
      int o = i >> 4, q = i & 15;
      *(float4v*)&VQ[o*64 + q*4] =
          *(const float4v*)(Vg + base + (size_t)o*Nn + m0 + q*4);
    }
    __syncthreads();

    // logits: s[i][j] = sum_o K[o][4rq+i] * V[o][2mq+j]
    float sv[4][2] = {};
    #pragma unroll 4
    for (int o = 0; o < Ci; ++o) {
      float4v kk = *(const float4v*)&Klds[o*32 + rq*4];
      float2  vv = *(const float2*)&VQ[o*64 + mq*2];
      #pragma unroll
      for (int i = 0; i < 4; ++i) { sv[i][0] += kk[i]*vv.x; sv[i][1] += kk[i]*vv.y; }
    }

    // online softmax over this tile (rows shared by 32 lanes: mq = low 5 bits)
    float tmax[4], f[4], ts[4], p0[4], p1[4];
    #pragma unroll
    for (int i = 0; i < 4; ++i) tmax[i] = fmaxf(sv[i][0], sv[i][1]);
    #pragma unroll
    for (int d = 16; d >= 1; d >>= 1)
      #pragma unroll
      for (int i = 0; i < 4; ++i) tmax[i] = fmaxf(tmax[i], __shfl_xor(tmax[i], d));
    #pragma unroll
    for (int i = 0; i < 4; ++i) {
      float mn = fmaxf(mrow[i], tmax[i]);
      f[i] = __expf(mrow[i] - mn);
      mrow[i] = mn;
      p0[i] = __expf(sv[i][0] - mn);
      p1[i] = __expf(sv[i][1] - mn);
      ts[i] = p0[i] + p1[i];
    }
    #pragma unroll
    for (int d = 16; d >= 1; d >>= 1)
      #pragma unroll
      for (int i = 0; i < 4; ++i) ts[i] += __shfl_xor(ts[i], d);
    #pragma unroll
    for (int i = 0; i < 4; ++i) {
      lrow[i] = lrow[i]*f[i] + ts[i];
      #pragma unroll
      for (int j = 0; j < 4; ++j) acc[i][j] *= f[i];
    }

    // store P transposed: Pt[m][r]
    float4v pa, pb_;
    #pragma unroll
    for (int i = 0; i < 4; ++i) { pa[i] = p0[i]; pb_[i] = p1[i]; }
    *(float4v*)&Pt[(mq*2+0)*36 + rq*4] = pa;
    *(float4v*)&Pt[(mq*2+1)*36 + rq*4] = pb_;
    __syncthreads();                                  // logits done with V

    for (int i = tid; i < Ci*16; i += 256) {          // Q tile, transposed
      int o = i >> 4, q = i & 15;
      float4v qv = *(const float4v*)(Qg + base + (size_t)o*Nn + m0 + q*4);
      VQ[(q*4+0)*132 + o] = qv[0];
      VQ[(q*4+1)*132 + o] = qv[1];
      VQ[(q*4+2)*132 + o] = qv[2];
      VQ[(q*4+3)*132 + o] = qv[3];
    }
    __syncthreads();

    // PV: acc[i][j] += P[4rq+i][m] * Q[m][4to+j]
    #pragma unroll 2
    for (int m = 0; m < 64; ++m) {
      float4v pp = *(const float4v*)&Pt[m*36 + rq*4];
      float4v qq = *(const float4v*)&VQ[m*132 + to*4];
      #pragma unroll
      for (int i = 0; i < 4; ++i)
        #pragma unroll
        for (int j = 0; j < 4; ++j) acc[i][j] += pp[i]*qq[j];
    }
  }

  // epilogue: scaled[b][o][r] = acc / l
  #pragma unroll
  for (int i = 0; i < 4; ++i) {
    float inv = 1.0f / lrow[i];
    #pragma unroll
    for (int j = 0; j < 4; ++j)
      Sg[base + (size_t)(to*4+j)*Nn + r0 + rq*4 + i] = acc[i][j] * inv;
  }
}

// ---------------------------------------------------------------------------
// Kernel 3: out[b][c][n] = sum_o w_w[c][o]*scaled[b][o][n] + w_b[c] + x
// ---------------------------------------------------------------------------
__global__ __launch_bounds__(256)
void out_kernel(const float* __restrict__ x,
                const float* __restrict__ ww, const float* __restrict__ wb,
                const float* __restrict__ Sg, float* __restrict__ out) {
  const int L  = blockIdx.x;      // 512
  const int s  = L & 15;
  const int b  = s & 3;
  const int n0 = (s >> 2) << 10;
  const int c0 = (L >> 4) * 8;

  __shared__ float Wl[Ci][8];     // [o][cc]
  for (int i = threadIdx.x; i < Ci*8; i += 256) {
    int cc = i >> 7, o = i & 127;
    Wl[o][cc] = ww[(size_t)(c0+cc)*Ci + o];
  }
  __syncthreads();

  const int n = n0 + threadIdx.x * 4;
  const float* Sp = Sg + (size_t)b*Ci*Nn + n;

  float acc[8][4];
  #pragma unroll
  for (int cc = 0; cc < 8; ++cc) {
    float bv = wb[c0+cc];
    #pragma unroll
    for (int k = 0; k < 4; ++k) acc[cc][k] = bv;
  }

  #pragma unroll 4
  for (int o = 0; o < Ci; ++o) {
    float4v svv = *(const float4v*)(Sp + (size_t)o*Nn);
    float4v wa  = *(const float4v*)&Wl[o][0];
    float4v wb4 = *(const float4v*)&Wl[o][4];
    #pragma unroll
    for (int cc = 0; cc < 4; ++cc)
      #pragma unroll
      for (int k = 0; k < 4; ++k) acc[cc][k]   += wa[cc]  * svv[k];
    #pragma unroll
    for (int cc = 0; cc < 4; ++cc)
      #pragma unroll
      for (int k = 0; k < 4; ++k) acc[cc+4][k] += wb4[cc] * svv[k];
  }

  #pragma unroll
  for (int cc = 0; cc < 8; ++cc) {
    const size_t off = (size_t)b*Cc*Nn + (size_t)(c0+cc)*Nn + n;
    float4v xv = *(const float4v*)(x + off);
    float4v r;
    #pragma unroll
    for (int k = 0; k < 4; ++k) r[k] = acc[cc][k] + xv[k];
    *(float4v*)(out + off) = r;
  }
}

extern "C" void kernel_launch(void* const* d_in, const int* in_sizes, int n_in,
                              void* d_out, int out_size, void* d_ws, size_t ws_size,
                              hipStream_t stream) {
  const float* x  = (const float*)d_in[0];
  const float* tw = (const float*)d_in[1];
  const float* tb = (const float*)d_in[2];
  const float* pw = (const float*)d_in[3];
  const float* pb = (const float*)d_in[4];
  const float* gw = (const float*)d_in[5];
  const float* gb = (const float*)d_in[6];
  const float* ww = (const float*)d_in[7];
  const float* wbb= (const float*)d_in[8];
  float* ws  = (float*)d_ws;
  float* out = (float*)d_out;

  // ws layout: K | V | Q | scaled, each Msz fp32 elements (32 MB total)
  if (ws_size < 4 * Msz * sizeof(float)) return;  // fail loudly if ws too small

  proj_kernel<<<768, 256, 0, stream>>>(x, tw, tb, pw, pb, gw, gb, ws);
  attn_kernel<<<512, 256, 0, stream>>>(ws, ws + 3*Msz);
  out_kernel<<<512, 256, 0, stream>>>(x, ww, wbb, ws + 3*Msz, out);
}

// Round 2
// 273.794 us; speedup vs baseline: 2.8050x; 2.8050x over previous
//
#include <hip/hip_runtime.h>
#include <hip/hip_bf16.h>
#include <math.h>

typedef float  float4v __attribute__((ext_vector_type(4)));
typedef float  f32x16  __attribute__((ext_vector_type(16)));
typedef short  short8v __attribute__((ext_vector_type(8)));   // 8 bf16 (4 VGPR)
typedef unsigned int   uN4 __attribute__((ext_vector_type(4)));
typedef unsigned short us4 __attribute__((ext_vector_type(4)));

constexpr int Bn  = 4;
constexpr int Cc  = 256;    // C_IN
constexpr int Ci  = 128;    // C_INT
constexpr int Nn  = 4096;   // H*W

// ws layout (ushort elements): bf16 tensors, each [4][4096][128] or [4][128][4096]
constexpr size_t KT_H = 0;                    // key^T   [b][n][o] hi
constexpr size_t KT_L = 2097152;              // key^T   lo
constexpr size_t VT_H = 4194304;              // value^T [b][m][o] hi
constexpr size_t VT_L = 6291456;              // value^T lo
constexpr size_t Q_H  = 8388608;              // query   [b][o][n] hi
constexpr size_t OB0  = 10485760;             // partial O (mh=0), [b][o][n], normalized, bf16
constexpr size_t OB1  = 12582912;             // partial O (mh=1)
constexpr size_t WS_STAT_BYTE = 28u*1024*1024;  // then Mst[2][4][4096], Lst[2][4][4096] fp32

__device__ __forceinline__ unsigned short f2bf(float x) {
  union { float f; unsigned u; } v; v.f = x;
  unsigned r = v.u + 0x7fff + ((v.u >> 16) & 1);     // RNE
  return (unsigned short)(r >> 16);
}
__device__ __forceinline__ float bf2f(unsigned short h) {
  union { unsigned u; float f; } v; v.u = ((unsigned)h) << 16; return v.f;
}
__device__ __forceinline__ f32x16 zero16() {
  f32x16 z;
  #pragma unroll
  for (int r = 0; r < 16; ++r) z[r] = 0.0f;
  return z;
}
__device__ __forceinline__ f32x16 mfma32(short8v a, short8v b, f32x16 c) {
  return __builtin_amdgcn_mfma_f32_32x32x16_bf16(a, b, c, 0, 0, 0);
}

// ---------------------------------------------------------------------------
// Kernel 1: projections (fp32 VALU compute, bf16 hi/lo stores).
// theta -> Kt[b][n][o] hi/lo ; phi -> Vt[b][m][o] hi/lo ; g -> Q[b][o][n] hi.
// ---------------------------------------------------------------------------
__global__ __launch_bounds__(256)
void proj_kernel(const float* __restrict__ x,
                 const float* __restrict__ tw, const float* __restrict__ tb,
                 const float* __restrict__ pw, const float* __restrict__ pb,
                 const float* __restrict__ gw, const float* __restrict__ gb,
                 unsigned short* __restrict__ ws16) {
  const int L  = blockIdx.x;
  const int s  = L & 15;
  const int b  = s & 3;
  const int n0 = (s >> 2) << 10;
  const int j0 = (L >> 4) * 8;            // stacked output row base (0..383)

  const float* W; const float* bias;
  if (j0 < 128)      { W = tw + (size_t)j0*Cc;       bias = tb + j0; }
  else if (j0 < 256) { W = pw + (size_t)(j0-128)*Cc; bias = pb + (j0-128); }
  else               { W = gw + (size_t)(j0-256)*Cc; bias = gb + (j0-256); }

  __shared__ float Wl[Cc][8];
  for (int i = threadIdx.x; i < 8*Cc; i += 256) {
    int jj = i >> 8, c = i & 255;
    Wl[c][jj] = W[(size_t)jj*Cc + c];
  }
  __syncthreads();

  const int nloc = n0 + threadIdx.x * 4;
  const float* xp = x + (size_t)b*Cc*Nn + nloc;

  float acc[8][4];
  #pragma unroll
  for (int jj = 0; jj < 8; ++jj) {
    float bv = bias[jj];
    #pragma unroll
    for (int k = 0; k < 4; ++k) acc[jj][k] = bv;
  }

  #pragma unroll 4
  for (int c = 0; c < Cc; ++c) {
    float4v xv = *(const float4v*)(xp + (size_t)c*Nn);
    float4v wa = *(const float4v*)&Wl[c][0];
    float4v wb4 = *(const float4v*)&Wl[c][4];
    #pragma unroll
    for (int jj = 0; jj < 4; ++jj)
      #pragma unroll
      for (int k = 0; k < 4; ++k) acc[jj][k]   += wa[jj]  * xv[k];
    #pragma unroll
    for (int jj = 0; jj < 4; ++jj)
      #pragma unroll
      for (int k = 0; k < 4; ++k) acc[jj+4][k] += wb4[jj] * xv[k];
  }

  const int jj0 = j0 & 127;
  if (j0 < 256) {
    // n-major transposed store, hi+lo
    const size_t baseH = (j0 < 128) ? KT_H : VT_H;
    const size_t baseL = (j0 < 128) ? KT_L : VT_L;
    #pragma unroll
    for (int k = 0; k < 4; ++k) {
      union { unsigned short s[8]; uN4 v; } H, Lo;
      #pragma unroll
      for (int jj = 0; jj < 8; ++jj) {
        float v_ = acc[jj][k];
        unsigned short h = f2bf(v_);
        H.s[jj]  = h;
        Lo.s[jj] = f2bf(v_ - bf2f(h));
      }
      size_t off = ((size_t)(b*4096 + nloc + k) << 7) + jj0;
      *(uN4*)(ws16 + baseH + off) = H.v;
      *(uN4*)(ws16 + baseL + off) = Lo.v;
    }
  } else {
    // o-major store, hi only
    #pragma unroll
    for (int jj = 0; jj < 8; ++jj) {
      us4 q;
      #pragma unroll
      for (int k = 0; k < 4; ++k) q[k] = f2bf(acc[jj][k]);
      *(us4*)(ws16 + Q_H + ((size_t)(b*128 + jj0 + jj) << 12) + nloc) = q;
    }
  }
}

// ---------------------------------------------------------------------------
// Kernel 2: flash attention, 32x32x16 bf16 MFMA, hi/lo 3-product logits.
// 4 waves x 32 rows = 128 rows/block; m-split in halves of 2048 (32 iters of 64).
// Grid 256: L = (rb<<3)|(mh<<2)|b  ->  XCD = 4*mh+b pins (batch, m-half) to one L2.
// LDS: double buf [Vh 16K|Vl 16K|Q 16K] x2 + P 16K = 112 KB, XOR-swizzled.
// ---------------------------------------------------------------------------
__device__ __forceinline__ void stage_load(const unsigned short* __restrict__ ws16,
                                           int b, int m0_, int tid, uN4* sv) {
  const unsigned short* VtH = ws16 + VT_H;
  const unsigned short* VtL = ws16 + VT_L;
  const unsigned short* Qh  = ws16 + Q_H;
  #pragma unroll
  for (int k = 0; k < 4; ++k) {
    int i = tid + (k << 8); int m = i >> 4, oc = i & 15;
    sv[k]     = *(const uN4*)(VtH + ((size_t)(b*4096 + m0_ + m) << 7) + oc*8);
  }
  #pragma unroll
  for (int k = 0; k < 4; ++k) {
    int i = tid + (k << 8); int m = i >> 4, oc = i & 15;
    sv[4 + k] = *(const uN4*)(VtL + ((size_t)(b*4096 + m0_ + m) << 7) + oc*8);
  }
  #pragma unroll
  for (int k = 0; k < 4; ++k) {
    int j = tid + (k << 8); int o = j >> 3, mc = j & 7;
    sv[8 + k] = *(const uN4*)(Qh + ((size_t)(b*128 + o) << 12) + m0_ + mc*8);
  }
}

__device__ __forceinline__ void stage_write(unsigned char* smem, int bufb, int tid,
                                            const uN4* sv) {
  #pragma unroll
  for (int k = 0; k < 4; ++k) {
    int i = tid + (k << 8); int m = i >> 4, oc = i & 15;
    *(uN4*)(smem + bufb +         m*256 + ((oc*16) ^ ((m & 15)*16))) = sv[k];
  }
  #pragma unroll
  for (int k = 0; k < 4; ++k) {
    int i = tid + (k << 8); int m = i >> 4, oc = i & 15;
    *(uN4*)(smem + bufb + 16384 + m*256 + ((oc*16) ^ ((m & 15)*16))) = sv[4 + k];
  }
  #pragma unroll
  for (int k = 0; k < 4; ++k) {
    int j = tid + (k << 8); int o = j >> 3, mc = j & 7;
    *(uN4*)(smem + bufb + 32768 + o*128 + ((mc*16) ^ ((o & 7)*16)))  = sv[8 + k];
  }
}

__global__ __launch_bounds__(256, 1)
void attn_kernel(unsigned short* __restrict__ ws16,
                 float* __restrict__ Mst, float* __restrict__ Lst) {
  const int L  = blockIdx.x;
  const int b  = L & 3;
  const int mh = (L >> 2) & 1;
  const int rb = L >> 3;
  const int r0 = rb * 128;
  const int mbase = mh * 2048;

  const int tid  = threadIdx.x;
  const int w    = tid >> 6;
  const int lane = tid & 63;
  const int l31  = lane & 31;
  const int g    = lane >> 5;

  __shared__ __align__(16) unsigned char smem[112 * 1024];
  constexpr int PB = 96 * 1024;

  // ---- K fragments (persistent, hi+lo): rows r0+32w+l31, k-slices of o ----
  const int nrow = r0 + w*32 + l31;
  short8v kh[8], kl[8];
  {
    const unsigned short* KtH = ws16 + KT_H + ((size_t)(b*4096 + nrow) << 7);
    const unsigned short* KtL = ws16 + KT_L + ((size_t)(b*4096 + nrow) << 7);
    #pragma unroll
    for (int kt = 0; kt < 8; ++kt) {
      kh[kt] = *(const short8v*)(KtH + kt*16 + g*8);
      kl[kt] = *(const short8v*)(KtL + kt*16 + g*8);
    }
  }

  f32x16 acc[4];
  #pragma unroll
  for (int ot = 0; ot < 4; ++ot) acc[ot] = zero16();
  float mreg[16], lreg[16];
  #pragma unroll
  for (int r = 0; r < 16; ++r) { mreg[r] = -INFINITY; lreg[r] = 0.0f; }

  uN4 sv[12];
  stage_load(ws16, b, mbase, tid, sv);
  stage_write(smem, 0, tid, sv);
  __syncthreads();

  for (int t = 0; t < 32; ++t) {
    const int cur  = t & 1;
    const int bufb = cur * 49152;
    if (t < 31) stage_load(ws16, b, mbase + (t + 1)*64, tid, sv);

    // ---- logits: S = Kh*Vh + Kh*Vl + Kl*Vh  (4 independent chains) ----
    f32x16 cc[2][2];
    cc[0][0] = zero16(); cc[0][1] = zero16();
    cc[1][0] = zero16(); cc[1][1] = zero16();
    #pragma unroll
    for (int kt = 0; kt < 8; ++kt) {
      #pragma unroll
      for (int sub = 0; sub < 2; ++sub) {
        const int m_ = sub*32 + l31;
        const int ob = (kt*32 + g*16) ^ ((m_ & 15)*16);
        short8v vh = *(const short8v*)(smem + bufb +         m_*256 + ob);
        short8v vl = *(const short8v*)(smem + bufb + 16384 + m_*256 + ob);
        f32x16 c = cc[kt & 1][sub];
        c = mfma32(kh[kt], vh, c);
        c = mfma32(kh[kt], vl, c);
        c = mfma32(kl[kt], vh, c);
        cc[kt & 1][sub] = c;
      }
    }
    f32x16 c0 = cc[0][0] + cc[1][0];
    f32x16 c1 = cc[0][1] + cc[1][1];

    // ---- online softmax over this 64-m tile (rows spread: 32 lanes/row) ----
    #pragma unroll
    for (int r = 0; r < 16; ++r) {
      float tm = fmaxf(c0[r], c1[r]);
      tm = fmaxf(tm, __shfl_xor(tm, 1));
      tm = fmaxf(tm, __shfl_xor(tm, 2));
      tm = fmaxf(tm, __shfl_xor(tm, 4));
      tm = fmaxf(tm, __shfl_xor(tm, 8));
      tm = fmaxf(tm, __shfl_xor(tm, 16));
      float mn = fmaxf(mreg[r], tm);
      float f  = __expf(mreg[r] - mn);
      mreg[r] = mn;
      float p0 = __expf(c0[r] - mn);
      float p1 = __expf(c1[r] - mn);
      c0[r] = p0; c1[r] = p1;
      float ts = p0 + p1;
      ts += __shfl_xor(ts, 1);
      ts += __shfl_xor(ts, 2);
      ts += __shfl_xor(ts, 4);
      ts += __shfl_xor(ts, 8);
      ts += __shfl_xor(ts, 16);
      lreg[r] = lreg[r]*f + ts;
      acc[0][r] *= f; acc[1][r] *= f; acc[2][r] *= f; acc[3][r] *= f;
    }

    // ---- P -> LDS (bf16, swizzled) ----
    #pragma unroll
    for (int r = 0; r < 16; ++r) {
      const int row  = (r & 3) + 8*(r >> 2) + 4*g;
      const int rswz = (row & 7) * 16;
      const int pbo  = PB + w*4096 + row*128;
      *(unsigned short*)(smem + pbo + ((l31*2)      ^ rswz)) = f2bf(c0[r]);
      *(unsigned short*)(smem + pbo + ((64 + l31*2) ^ rswz)) = f2bf(c1[r]);
    }

    // ---- PV: acc[ot] += P(32n x 16m) * Q(16m x 32o) ----
    const int prswz = (l31 & 7) * 16;
    #pragma unroll
    for (int kt2 = 0; kt2 < 4; ++kt2) {
      const int mo = kt2*32 + g*16;
      short8v pf = *(const short8v*)(smem + PB + w*4096 + l31*128 + (mo ^ prswz));
      #pragma unroll
      for (int ot = 0; ot < 4; ++ot) {
        const int o_ = ot*32 + l31;
        short8v qf = *(const short8v*)(smem + bufb + 32768 + o_*128 + (mo ^ prswz));
        acc[ot] = mfma32(pf, qf, acc[ot]);
      }
    }

    if (t < 31) stage_write(smem, bufb ^ 49152, tid, sv);
    __syncthreads();
  }

  // ---- epilogue: normalized partial O (bf16) + stats ----
  unsigned short* Ob = ws16 + (mh ? OB1 : OB0);
  #pragma unroll
  for (int r = 0; r < 16; ++r) {
    const int row = (r & 3) + 8*(r >> 2) + 4*g;
    const int n_  = r0 + w*32 + row;
    const float inv = 1.0f / lreg[r];
    #pragma unroll
    for (int ot = 0; ot < 4; ++ot) {
      const int o_ = ot*32 + l31;
      Ob[((size_t)(b*128 + o_) << 12) + n_] = f2bf(acc[ot][r] * inv);
    }
    if (l31 == 0) {
      Mst[((mh*4 + b) << 12) + n_] = mreg[r];
      Lst[((mh*4 + b) << 12) + n_] = lreg[r];
    }
  }
}

// ---------------------------------------------------------------------------
// Kernel 3: merge m-halves + out projection + bias + residual.
// out[b][c][n] = sum_o w[c][o]*(c0[n]*O0[o][n] + c1[n]*O1[o][n]) + wb[c] + x
// ---------------------------------------------------------------------------
__global__ __launch_bounds__(256)
void out_kernel(const float* __restrict__ x,
                const float* __restrict__ ww, const float* __restrict__ wb,
                const unsigned short* __restrict__ ws16,
                const float* __restrict__ Mst, const float* __restrict__ Lst,
                float* __restrict__ out) {
  const int L  = blockIdx.x;      // 512
  const int s  = L & 15;
  const int b  = s & 3;
  const int n0 = (s >> 2) << 10;
  const int c0 = (L >> 4) * 8;

  __shared__ float Wl[Ci][8];
  __shared__ float c0s[1024], c1s[1024];

  for (int i = threadIdx.x; i < Ci*8; i += 256) {
    int cc = i >> 7, o = i & 127;
    Wl[o][cc] = ww[(size_t)(c0 + cc)*Ci + o];
  }
  #pragma unroll
  for (int k = 0; k < 4; ++k) {
    int nl = threadIdx.x*4 + k;
    int n_ = n0 + nl;
    float m0v = Mst[(b << 12) + n_],       l0v = Lst[(b << 12) + n_];
    float m1v = Mst[((4 + b) << 12) + n_], l1v = Lst[((4 + b) << 12) + n_];
    float M  = fmaxf(m0v, m1v);
    float w0 = l0v * __expf(m0v - M);
    float w1 = l1v * __expf(m1v - M);
    float inv = 1.0f / (w0 + w1);
    c0s[nl] = w0 * inv;
    c1s[nl] = w1 * inv;
  }
  __syncthreads();

  const int nloc = n0 + threadIdx.x * 4;
  const unsigned short* O0 = ws16 + OB0;
  const unsigned short* O1 = ws16 + OB1;
  float4v c0v = *(const float4v*)&c0s[threadIdx.x*4];
  float4v c1v = *(const float4v*)&c1s[threadIdx.x*4];

  float acc[8][4];
  #pragma unroll
  for (int cc = 0; cc < 8; ++cc) {
    float bv = wb[c0 + cc];
    #pragma unroll
    for (int k = 0; k < 4; ++k) acc[cc][k] = bv;
  }

  #pragma unroll 2
  for (int o = 0; o < Ci; ++o) {
    us4 u0 = *(const us4*)(O0 + ((size_t)(b*128 + o) << 12) + nloc);
    us4 u1 = *(const us4*)(O1 + ((size_t)(b*128 + o) << 12) + nloc);
    float4v svv;
    #pragma unroll
    for (int k = 0; k < 4; ++k)
      svv[k] = c0v[k]*bf2f(u0[k]) + c1v[k]*bf2f(u1[k]);
    float4v wa  = *(const float4v*)&Wl[o][0];
    float4v wb4 = *(const float4v*)&Wl[o][4];
    #pragma unroll
    for (int cc = 0; cc < 4; ++cc)
      #pragma unroll
      for (int k = 0; k < 4; ++k) acc[cc][k]   += wa[cc]  * svv[k];
    #pragma unroll
    for (int cc = 0; cc < 4; ++cc)
      #pragma unroll
      for (int k = 0; k < 4; ++k) acc[cc+4][k] += wb4[cc] * svv[k];
  }

  #pragma unroll
  for (int cc = 0; cc < 8; ++cc) {
    const size_t off = (size_t)b*Cc*Nn + (size_t)(c0 + cc)*Nn + nloc;
    float4v xv = *(const float4v*)(x + off);
    float4v r;
    #pragma unroll
    for (int k = 0; k < 4; ++k) r[k] = acc[cc][k] + xv[k];
    *(float4v*)(out + off) = r;
  }
}

extern "C" void kernel_launch(void* const* d_in, const int* in_sizes, int n_in,
                              void* d_out, int out_size, void* d_ws, size_t ws_size,
                              hipStream_t stream) {
  const float* x  = (const float*)d_in[0];
  const float* tw = (const float*)d_in[1];
  const float* tb = (const float*)d_in[2];
  const float* pw = (const float*)d_in[3];
  const float* pb = (const float*)d_in[4];
  const float* gw = (const float*)d_in[5];
  const float* gb = (const float*)d_in[6];
  const float* ww = (const float*)d_in[7];
  const float* wbb= (const float*)d_in[8];

  unsigned short* ws16 = (unsigned short*)d_ws;
  float* Mst = (float*)((char*)d_ws + WS_STAT_BYTE);
  float* Lst = Mst + 2*4*4096;
  float* out = (float*)d_out;

  // need 28 MB bf16 tensors + 256 KB stats
  if (ws_size < WS_STAT_BYTE + 2u*2*4*4096*sizeof(float)) return;

  proj_kernel<<<768, 256, 0, stream>>>(x, tw, tb, pw, pb, gw, gb, ws16);
  attn_kernel<<<256, 256, 0, stream>>>(ws16, Mst, Lst);
  out_kernel<<<512, 256, 0, stream>>>(x, ww, wbb, ws16, Mst, Lst, out);
}

// Round 4
// 161.942 us; speedup vs baseline: 4.7424x; 1.6907x over previous
//
#include <hip/hip_runtime.h>
#include <hip/hip_bf16.h>
#include <math.h>

typedef float  float4v __attribute__((ext_vector_type(4)));
typedef float  f32x16  __attribute__((ext_vector_type(16)));
typedef _Float16 half8  __attribute__((ext_vector_type(8)));
typedef __fp16  fp16x2 __attribute__((ext_vector_type(2)));
typedef unsigned int   uN4 __attribute__((ext_vector_type(4)));
typedef unsigned int   uN2 __attribute__((ext_vector_type(2)));
typedef unsigned short us4 __attribute__((ext_vector_type(4)));

constexpr int Cc = 256;    // C_IN
constexpr int Ci = 128;    // C_INT
constexpr int Nn = 4096;   // H*W

// ws layout (ushort units). All fp16.
constexpr size_t KT  = 0;          // K [b][n][o]   (4 MB)
constexpr size_t VT  = 2097152;    // V [b][m][o]   (4 MB)
constexpr size_t QT  = 4194304;    // Q [b][o][n]   (4 MB)
constexpr size_t OB  = 6291456;    // O partials [mh][b][o][n], 4 x 4 MB
constexpr size_t OSZ = 2097152;
constexpr size_t STAT_BYTE = 29360128;  // 28 MB; then Mst[16][4096], Lst[16][4096] f32

__device__ __forceinline__ f32x16 zero16() {
  f32x16 z;
  #pragma unroll
  for (int r = 0; r < 16; ++r) z[r] = 0.0f;
  return z;
}
__device__ __forceinline__ unsigned pkf(float x, float y) {
  union { fp16x2 h; unsigned u; } c;
  c.h = __builtin_amdgcn_cvt_pkrtz(x, y);
  return c.u;
}
__device__ __forceinline__ f32x16 mfmaf16(half8 a, half8 b, f32x16 c) {
  return __builtin_amdgcn_mfma_f32_32x32x16_f16(a, b, c, 0, 0, 0);
}
__device__ __forceinline__ float h2f(unsigned short u) {
  union { unsigned short u; _Float16 h; } c; c.u = u; return (float)c.h;
}
__device__ __forceinline__ unsigned short f2h(float x) {
  union { _Float16 h; unsigned short u; } c; c.h = (_Float16)x; return c.u;
}

// Build PV A-fragment word set from this lane's 8 P-values (one kt2 slice).
// Lane (g,l31) ends with P[n=l31][m = kt2*16 + g*8 + e], e=0..7.
__device__ __forceinline__ half8 build_pfrag(float q0, float q1, float q2, float q3,
                                             float q4, float q5, float q6, float q7,
                                             int g) {
  unsigned a0 = pkf(q0, q1), a1 = pkf(q2, q3);
  unsigned b0 = pkf(q4, q5), b1 = pkf(q6, q7);
  unsigned xa0 = (unsigned)__shfl_xor((int)a0, 32);
  unsigned xa1 = (unsigned)__shfl_xor((int)a1, 32);
  unsigned xb0 = (unsigned)__shfl_xor((int)b0, 32);
  unsigned xb1 = (unsigned)__shfl_xor((int)b1, 32);
  union { unsigned u[4]; half8 h; } r;
  r.u[0] = g ? xb0 : a0;
  r.u[1] = g ? xb1 : a1;
  r.u[2] = g ? b0 : xa0;
  r.u[3] = g ? b1 : xa1;
  return r.h;
}

// ---------------------------------------------------------------------------
// Kernel 1: projections (fp32 VALU, fp16 stores). 16 j-rows per block.
// theta -> K[b][n][o], phi -> V[b][m][o], g -> Q[b][o][n].
// ---------------------------------------------------------------------------
__global__ __launch_bounds__(256)
void proj_kernel(const float* __restrict__ x,
                 const float* __restrict__ tw, const float* __restrict__ tb,
                 const float* __restrict__ pw, const float* __restrict__ pb,
                 const float* __restrict__ gw, const float* __restrict__ gb,
                 unsigned short* __restrict__ ws16) {
  const int L  = blockIdx.x;            // 384
  const int s  = L & 15;
  const int b  = s & 3;
  const int n0 = (s >> 2) << 10;
  const int j0 = (L >> 4) * 16;

  const float* W; const float* bias;
  if (j0 < 128)      { W = tw + (size_t)j0*Cc;       bias = tb + j0; }
  else if (j0 < 256) { W = pw + (size_t)(j0-128)*Cc; bias = pb + (j0-128); }
  else               { W = gw + (size_t)(j0-256)*Cc; bias = gb + (j0-256); }

  __shared__ float Wl[Cc][16];
  for (int i = threadIdx.x; i < 16*Cc; i += 256) {
    int jj = i >> 8, c = i & 255;
    Wl[c][jj] = W[(size_t)jj*Cc + c];
  }
  __syncthreads();

  const int nloc = n0 + threadIdx.x * 4;
  const float* xp = x + (size_t)b*Cc*Nn + nloc;

  float acc[16][4];
  #pragma unroll
  for (int jj = 0; jj < 16; ++jj) {
    float bv = bias[jj];
    #pragma unroll
    for (int k = 0; k < 4; ++k) acc[jj][k] = bv;
  }

  #pragma unroll 2
  for (int c = 0; c < Cc; ++c) {
    float4v xv = *(const float4v*)(xp + (size_t)c*Nn);
    #pragma unroll
    for (int q = 0; q < 4; ++q) {
      float4v wv = *(const float4v*)&Wl[c][q*4];
      #pragma unroll
      for (int j = 0; j < 4; ++j)
        #pragma unroll
        for (int k = 0; k < 4; ++k) acc[q*4+j][k] += wv[j]*xv[k];
    }
  }

  if (j0 < 256) {
    unsigned short* base = ws16 + ((j0 < 128) ? KT : VT);
    const int jj0 = j0 & 127;
    #pragma unroll
    for (int k = 0; k < 4; ++k) {
      union { unsigned short su[16]; uN4 v[2]; } P_;
      #pragma unroll
      for (int jj = 0; jj < 16; ++jj) P_.su[jj] = f2h(acc[jj][k]);
      size_t off = ((size_t)(b*4096 + nloc + k) << 7) + jj0;
      *(uN4*)(base + off)     = P_.v[0];
      *(uN4*)(base + off + 8) = P_.v[1];
    }
  } else {
    const int jj0 = j0 - 256;
    #pragma unroll
    for (int jj = 0; jj < 16; ++jj) {
      union { unsigned short su[4]; uN2 v; } P_;
      #pragma unroll
      for (int k = 0; k < 4; ++k) P_.su[k] = f2h(acc[jj][k]);
      *(uN2*)(ws16 + QT + ((size_t)(b*128 + jj0 + jj) << 12) + nloc) = P_.v;
    }
  }
}

// ---------------------------------------------------------------------------
// Kernel 2: flash attention, fp16 MFMA, swapped QK^T (lane-local softmax rows).
// 4 waves x 32 rows = 128 rows/block; m-split x4 (1024 m each, 16 tiles of 64).
// Grid 512 = 2 blocks/CU. LDS: double-buffered [V 16K | Q 16K] = 64 KB.
// ---------------------------------------------------------------------------
__device__ __forceinline__ void stage_load(const unsigned short* __restrict__ ws16,
                                           int b, int m0_, int tid, uN4* sv) {
  const unsigned short* Vt = ws16 + VT;
  const unsigned short* Qh = ws16 + QT;
  #pragma unroll
  for (int k = 0; k < 4; ++k) {
    int i = tid + (k << 8); int m = i >> 4, oc = i & 15;
    sv[k] = *(const uN4*)(Vt + (((size_t)(b*4096 + m0_ + m)) << 7) + oc*8);
  }
  #pragma unroll
  for (int k = 0; k < 4; ++k) {
    int j = tid + (k << 8); int o = j >> 3, mc = j & 7;
    sv[4+k] = *(const uN4*)(Qh + (((size_t)(b*128 + o)) << 12) + m0_ + mc*8);
  }
}
__device__ __forceinline__ void stage_write(unsigned char* dst, int tid, const uN4* sv) {
  #pragma unroll
  for (int k = 0; k < 4; ++k) {
    int i = tid + (k << 8); int m = i >> 4, oc = i & 15;
    *(uN4*)(dst + m*256 + ((oc*16) ^ ((m & 15)*16))) = sv[k];
  }
  #pragma unroll
  for (int k = 0; k < 4; ++k) {
    int j = tid + (k << 8); int o = j >> 3, mc = j & 7;
    *(uN4*)(dst + 16384 + o*128 + ((mc*16) ^ ((o & 7)*16))) = sv[4+k];
  }
}

__global__ __launch_bounds__(256, 2)
void attn_kernel(unsigned short* __restrict__ ws16,
                 float* __restrict__ Mst, float* __restrict__ Lst) {
  const int L  = blockIdx.x;            // 512
  const int b  = L & 3;
  const int mh = (L >> 2) & 3;
  const int rb = L >> 4;
  const int r0 = rb * 128;
  const int mbase = mh * 1024;
  constexpr int NT = 16;

  const int tid  = threadIdx.x;
  const int w    = tid >> 6;
  const int lane = tid & 63;
  const int l31  = lane & 31;
  const int g    = lane >> 5;

  __shared__ __align__(16) unsigned char smem[65536];

  // persistent K fragments: this lane's B-frag column = row n = r0 + 32w + l31
  const int nrow = r0 + w*32 + l31;
  half8 kh[8];
  {
    const unsigned short* Kt = ws16 + KT + (((size_t)(b*4096 + nrow)) << 7);
    #pragma unroll
    for (int kt = 0; kt < 8; ++kt)
      kh[kt] = *(const half8*)(Kt + kt*16 + g*8);
  }

  f32x16 acc[4];
  #pragma unroll
  for (int ot = 0; ot < 4; ++ot) acc[ot] = zero16();
  float mreg = -INFINITY, lreg = 0.0f;

  uN4 sv[8];
  stage_load(ws16, b, mbase, tid, sv);
  stage_write(smem, tid, sv);
  __syncthreads();

  for (int t = 0; t < NT; ++t) {
    unsigned char* buf  = smem + ((t & 1) << 15);
    unsigned char* nbuf = smem + (((t & 1) ^ 1) << 15);
    if (t + 1 < NT) stage_load(ws16, b, mbase + (t+1)*64, tid, sv);

    // ---- logits: S^T = V * K  (A = V rows m, B = K cols n) ----
    f32x16 c0 = zero16(), c1 = zero16();
    __builtin_amdgcn_s_setprio(1);
    #pragma unroll
    for (int kt = 0; kt < 8; ++kt) {
      const int ob = (kt*32 + g*16) ^ ((l31 & 15)*16);
      half8 v0 = *(const half8*)(buf + l31*256 + ob);
      half8 v1 = *(const half8*)(buf + (32 + l31)*256 + ob);   // same swizzle: (32+l31)&15 == l31&15
      c0 = mfmaf16(v0, kh[kt], c0);
      c1 = mfmaf16(v1, kh[kt], c1);
    }
    __builtin_amdgcn_s_setprio(0);

    // ---- softmax: lane owns row n = l31 (both g-halves) ----
    float tm = fmaxf(c0[0], c1[0]);
    #pragma unroll
    for (int r = 1; r < 16; ++r) tm = fmaxf(tm, fmaxf(c0[r], c1[r]));
    tm = fmaxf(tm, __shfl_xor(tm, 32));

    float f = 1.0f;
    if (__any(tm > mreg + 8.0f)) {        // T13 defer-max
      float mn = fmaxf(mreg, tm);
      f = __expf(mreg - mn);
      mreg = mn;
      #pragma unroll
      for (int r = 0; r < 16; ++r) {
        const int nl = (r & 3) + 8*(r >> 2) + 4*g;
        float fr = __shfl(f, nl);
        acc[0][r] *= fr; acc[1][r] *= fr; acc[2][r] *= fr; acc[3][r] *= fr;
      }
    }
    float ts = 0.0f;
    #pragma unroll
    for (int r = 0; r < 16; ++r) { c0[r] = __expf(c0[r] - mreg); ts += c0[r]; }
    #pragma unroll
    for (int r = 0; r < 16; ++r) { c1[r] = __expf(c1[r] - mreg); ts += c1[r]; }
    ts += __shfl_xor(ts, 32);
    lreg = lreg * f + ts;

    // ---- P -> PV A-fragments, fully in-register ----
    half8 pfr[4];
    pfr[0] = build_pfrag(c0[0],c0[1],c0[2],c0[3],c0[4],c0[5],c0[6],c0[7], g);
    pfr[1] = build_pfrag(c0[8],c0[9],c0[10],c0[11],c0[12],c0[13],c0[14],c0[15], g);
    pfr[2] = build_pfrag(c1[0],c1[1],c1[2],c1[3],c1[4],c1[5],c1[6],c1[7], g);
    pfr[3] = build_pfrag(c1[8],c1[9],c1[10],c1[11],c1[12],c1[13],c1[14],c1[15], g);

    // ---- PV: acc[ot](32n x 32o) += P(32n x 16m) * Q(16m x 32o) ----
    __builtin_amdgcn_s_setprio(1);
    #pragma unroll
    for (int kt2 = 0; kt2 < 4; ++kt2) {
      const int qo = kt2*32 + g*16;
      #pragma unroll
      for (int ot = 0; ot < 4; ++ot) {
        const int o_ = ot*32 + l31;
        half8 qf = *(const half8*)(buf + 16384 + o_*128 + (qo ^ ((o_ & 7)*16)));
        acc[ot] = mfmaf16(pfr[kt2], qf, acc[ot]);
      }
    }
    __builtin_amdgcn_s_setprio(0);

    if (t + 1 < NT) stage_write(nbuf, tid, sv);
    __syncthreads();
  }

  // ---- epilogue: normalized fp16 partial + stats ----
  unsigned short* Ob = ws16 + OB + (size_t)mh*OSZ;
  const float linv_own = 1.0f / lreg;
  #pragma unroll
  for (int r = 0; r < 16; ++r) {
    const int nl = (r & 3) + 8*(r >> 2) + 4*g;
    const float linv = __shfl(linv_own, nl);
    const int n_ = r0 + w*32 + nl;
    #pragma unroll
    for (int ot = 0; ot < 4; ++ot) {
      const int o_ = ot*32 + l31;
      Ob[(((size_t)(b*128 + o_)) << 12) + n_] = f2h(acc[ot][r] * linv);
    }
  }
  if (lane < 32) {
    const int n_ = r0 + w*32 + l31;
    Mst[((mh*4 + b) << 12) + n_] = mreg;
    Lst[((mh*4 + b) << 12) + n_] = lreg;
  }
}

// ---------------------------------------------------------------------------
// Kernel 3: merge 4 m-partials + out projection + bias + residual. 16 c/block.
// ---------------------------------------------------------------------------
__global__ __launch_bounds__(256)
void out_kernel(const float* __restrict__ x,
                const float* __restrict__ ww, const float* __restrict__ wb,
                const unsigned short* __restrict__ ws16,
                const float* __restrict__ Mst, const float* __restrict__ Lst,
                float* __restrict__ out) {
  const int L  = blockIdx.x;            // 256
  const int s  = L & 15;
  const int b  = s & 3;
  const int n0 = (s >> 2) << 10;
  const int c0_ = (L >> 4) * 16;

  __shared__ float Wl[Ci][16];
  __shared__ float cs[4][1024];

  for (int i = threadIdx.x; i < Ci*16; i += 256) {
    int cc = i >> 7, o = i & 127;
    Wl[o][cc] = ww[(size_t)(c0_ + cc)*Ci + o];
  }
  #pragma unroll
  for (int k = 0; k < 4; ++k) {
    int nl = threadIdx.x*4 + k;
    int n_ = n0 + nl;
    float m0v = Mst[((0*4+b) << 12) + n_], l0v = Lst[((0*4+b) << 12) + n_];
    float m1v = Mst[((1*4+b) << 12) + n_], l1v = Lst[((1*4+b) << 12) + n_];
    float m2v = Mst[((2*4+b) << 12) + n_], l2v = Lst[((2*4+b) << 12) + n_];
    float m3v = Mst[((3*4+b) << 12) + n_], l3v = Lst[((3*4+b) << 12) + n_];
    float M = fmaxf(fmaxf(m0v, m1v), fmaxf(m2v, m3v));
    float w0 = l0v * __expf(m0v - M);
    float w1 = l1v * __expf(m1v - M);
    float w2 = l2v * __expf(m2v - M);
    float w3 = l3v * __expf(m3v - M);
    float inv = 1.0f / (w0 + w1 + w2 + w3);
    cs[0][nl] = w0*inv; cs[1][nl] = w1*inv; cs[2][nl] = w2*inv; cs[3][nl] = w3*inv;
  }
  __syncthreads();

  const int nloc = n0 + threadIdx.x * 4;
  float4v cv0 = *(const float4v*)&cs[0][threadIdx.x*4];
  float4v cv1 = *(const float4v*)&cs[1][threadIdx.x*4];
  float4v cv2 = *(const float4v*)&cs[2][threadIdx.x*4];
  float4v cv3 = *(const float4v*)&cs[3][threadIdx.x*4];

  float acc[16][4];
  #pragma unroll
  for (int cc = 0; cc < 16; ++cc) {
    float bv = wb[c0_ + cc];
    #pragma unroll
    for (int k = 0; k < 4; ++k) acc[cc][k] = bv;
  }

  const unsigned short* O0 = ws16 + OB;
  #pragma unroll 2
  for (int o = 0; o < Ci; ++o) {
    const size_t ro = (((size_t)(b*128 + o)) << 12) + nloc;
    us4 u0 = *(const us4*)(O0 + ro);
    us4 u1 = *(const us4*)(O0 + OSZ + ro);
    us4 u2 = *(const us4*)(O0 + 2*OSZ + ro);
    us4 u3 = *(const us4*)(O0 + 3*OSZ + ro);
    float4v svv;
    #pragma unroll
    for (int k = 0; k < 4; ++k)
      svv[k] = cv0[k]*h2f(u0[k]) + cv1[k]*h2f(u1[k]) + cv2[k]*h2f(u2[k]) + cv3[k]*h2f(u3[k]);
    #pragma unroll
    for (int q = 0; q < 4; ++q) {
      float4v wv = *(const float4v*)&Wl[o][q*4];
      #pragma unroll
      for (int j = 0; j < 4; ++j)
        #pragma unroll
        for (int k = 0; k < 4; ++k) acc[q*4+j][k] += wv[j]*svv[k];
    }
  }

  #pragma unroll
  for (int cc = 0; cc < 16; ++cc) {
    const size_t off = (size_t)b*Cc*Nn + (size_t)(c0_ + cc)*Nn + nloc;
    float4v xv = *(const float4v*)(x + off);
    float4v r;
    #pragma unroll
    for (int k = 0; k < 4; ++k) r[k] = acc[cc][k] + xv[k];
    *(float4v*)(out + off) = r;
  }
}

extern "C" void kernel_launch(void* const* d_in, const int* in_sizes, int n_in,
                              void* d_out, int out_size, void* d_ws, size_t ws_size,
                              hipStream_t stream) {
  const float* x  = (const float*)d_in[0];
  const float* tw = (const float*)d_in[1];
  const float* tb = (const float*)d_in[2];
  const float* pw = (const float*)d_in[3];
  const float* pb = (const float*)d_in[4];
  const float* gw = (const float*)d_in[5];
  const float* gb = (const float*)d_in[6];
  const float* ww = (const float*)d_in[7];
  const float* wbb= (const float*)d_in[8];

  unsigned short* ws16 = (unsigned short*)d_ws;
  float* Mst = (float*)((char*)d_ws + STAT_BYTE);
  float* Lst = Mst + 16*4096;
  float* out = (float*)d_out;

  if (ws_size < STAT_BYTE + 2u*16*4096*sizeof(float)) return;  // 28.5 MB needed

  proj_kernel<<<384, 256, 0, stream>>>(x, tw, tb, pw, pb, gw, gb, ws16);
  attn_kernel<<<512, 256, 0, stream>>>(ws16, Mst, Lst);
  out_kernel<<<256, 256, 0, stream>>>(x, ww, wbb, ws16, Mst, Lst, out);
}

// Round 5
// 95.491 us; speedup vs baseline: 8.0426x; 1.6959x over previous
//
#include <hip/hip_runtime.h>
#include <hip/hip_bf16.h>
#include <math.h>

typedef float  float4v __attribute__((ext_vector_type(4)));
typedef float  f32x16  __attribute__((ext_vector_type(16)));
typedef _Float16 half8  __attribute__((ext_vector_type(8)));
typedef _Float16 h2v    __attribute__((ext_vector_type(2)));
typedef __fp16  fp16x2 __attribute__((ext_vector_type(2)));
typedef unsigned int   uN4 __attribute__((ext_vector_type(4)));
typedef unsigned short us4 __attribute__((ext_vector_type(4)));

constexpr int Cc = 256;    // C_IN
constexpr int Ci = 128;    // C_INT
constexpr int Nn = 4096;   // H*W

// ws layout (ushort units). All fp16 unless noted.
constexpr size_t KT  = 0;          // K [b][n][o]   (4 MB)
constexpr size_t VT  = 2097152;    // V [b][m][o]   (4 MB)
constexpr size_t QT  = 4194304;    // Q [b][o][n]   (4 MB)
constexpr size_t OB  = 6291456;    // O partials [mh][b][n][o], 4 x 4 MB
constexpr size_t OSZ = 2097152;
constexpr size_t XH  = 6291456;    // x^T [b][n][c] fp16 (8 MB) — ALIASES OB[0..1]
                                   // (dead after proj; attn writes OB later)
constexpr size_t STAT_BYTE = 29360128;  // Mst[16][4096], Lst[16][4096] f32 (512 KB)
constexpr size_t WH  = 14942208;   // stacked weights fp16 [384][256] (theta,phi,g)
constexpr size_t WOH = 15040512;   // w_w fp16 [256][128]
// end: ushort 15073280 = byte 30146560  (ws >= 33554432 proven in round 1)

__device__ __forceinline__ f32x16 zero16() {
  f32x16 z;
  #pragma unroll
  for (int r = 0; r < 16; ++r) z[r] = 0.0f;
  return z;
}
__device__ __forceinline__ unsigned pkf(float x, float y) {
  union { fp16x2 h; unsigned u; } c;
  c.h = __builtin_amdgcn_cvt_pkrtz(x, y);
  return c.u;
}
__device__ __forceinline__ f32x16 mfmaf16(half8 a, half8 b, f32x16 c) {
  return __builtin_amdgcn_mfma_f32_32x32x16_f16(a, b, c, 0, 0, 0);
}
__device__ __forceinline__ float h2f(unsigned short u) {
  union { unsigned short u; _Float16 h; } c; c.u = u; return (float)c.h;
}
__device__ __forceinline__ unsigned short f2h(float x) {
  union { _Float16 h; unsigned short u; } c; c.h = (_Float16)x; return c.u;
}
__device__ __forceinline__ unsigned pkfma(unsigned a, unsigned b, unsigned c) {
  union { unsigned u; h2v h; } A, B, C, R;
  A.u = a; B.u = b; C.u = c;
  R.h = A.h * B.h + C.h;
  return R.u;
}
__device__ __forceinline__ unsigned pkmul(unsigned a, unsigned b) {
  union { unsigned u; h2v h; } A, B, R;
  A.u = a; B.u = b;
  R.h = A.h * B.h;
  return R.u;
}

// Build PV A-fragment word set from this lane's 8 P-values (one kt2 slice).
__device__ __forceinline__ half8 build_pfrag(float q0, float q1, float q2, float q3,
                                             float q4, float q5, float q6, float q7,
                                             int g) {
  unsigned a0 = pkf(q0, q1), a1 = pkf(q2, q3);
  unsigned b0 = pkf(q4, q5), b1 = pkf(q6, q7);
  unsigned xa0 = (unsigned)__shfl_xor((int)a0, 32);
  unsigned xa1 = (unsigned)__shfl_xor((int)a1, 32);
  unsigned xb0 = (unsigned)__shfl_xor((int)b0, 32);
  unsigned xb1 = (unsigned)__shfl_xor((int)b1, 32);
  union { unsigned u[4]; half8 h; } r;
  r.u[0] = g ? xb0 : a0;
  r.u[1] = g ? xb1 : a1;
  r.u[2] = g ? b0 : xa0;
  r.u[3] = g ? b1 : xa1;
  return r.h;
}

// ---------------------------------------------------------------------------
// Kernel 0: prep — x[b][c][n] f32 -> xT[b][n][c] fp16 (64x64 LDS transpose);
// blocks 0..127 additionally convert weights to fp16 (stacked WH + WOH).
// ---------------------------------------------------------------------------
__global__ __launch_bounds__(256)
void prep_kernel(const float* __restrict__ x,
                 const float* __restrict__ tw, const float* __restrict__ pw,
                 const float* __restrict__ gw, const float* __restrict__ ww,
                 unsigned short* __restrict__ ws16) {
  const int L = blockIdx.x;            // 1024 = b(4) x nt(64) x ct(4)
  const int b = L >> 8, rem = L & 255, nt = rem >> 2, ct = rem & 3;
  const int n0 = nt * 64, c0 = ct * 64;
  __shared__ unsigned short T[64][68];
  const int tid = threadIdx.x;
  const int tn = (tid & 15) * 4, tc = tid >> 4;

  #pragma unroll
  for (int it = 0; it < 4; ++it) {
    const int c = it*16 + tc;
    float4v v = *(const float4v*)(x + (((size_t)(b*256 + c0 + c)) << 12) + n0 + tn);
    #pragma unroll
    for (int k = 0; k < 4; ++k) T[tn + k][c] = f2h(v[k]);
  }

  if (L < 128) {    // weight conversion fold (131072 elems total)
    int i = L*1024 + tid*4;
    const float* src; unsigned short* dst;
    if (i < 32768)      { src = tw + i;           dst = ws16 + WH + i; }
    else if (i < 65536) { src = pw + (i - 32768); dst = ws16 + WH + i; }
    else if (i < 98304) { src = gw + (i - 65536); dst = ws16 + WH + i; }
    else                { src = ww + (i - 98304); dst = ws16 + WOH + (i - 98304); }
    float4v v = *(const float4v*)src;
    us4 o;
    #pragma unroll
    for (int k = 0; k < 4; ++k) o[k] = f2h(v[k]);
    *(us4*)dst = o;
  }
  __syncthreads();

  const int wn = tid >> 4, wc = (tid & 15) * 4;
  #pragma unroll
  for (int it = 0; it < 4; ++it) {
    const int n = it*16 + wn;
    us4 o;
    #pragma unroll
    for (int k = 0; k < 4; ++k) o[k] = T[n][wc + k];
    *(us4*)(ws16 + XH + (((size_t)(b*4096 + n0 + n)) << 8) + c0 + wc) = o;
  }
}

// ---------------------------------------------------------------------------
// Kernel 1: projections via MFMA, no LDS. 384 blocks: p(3) x b(4) x nt(32).
// p=0: K[b][n][o], p=1: V[b][m][o]  (D rows=n, cols=o -> coalesced o stores)
// p=2: Q[b][o][n]                   (D rows=o, cols=n -> coalesced n stores)
// ---------------------------------------------------------------------------
__global__ __launch_bounds__(256)
void proj_kernel(const float* __restrict__ tb, const float* __restrict__ pb,
                 const float* __restrict__ gb, unsigned short* __restrict__ ws16) {
  const int L = blockIdx.x;          // 384
  const int p = L >> 7;              // 0=K,1=V,2=Q
  const int rem = L & 127;
  const int b = rem & 3, nt = rem >> 2;
  const int n0 = nt * 128;
  const int tid = threadIdx.x, w = tid >> 6, lane = tid & 63;
  const int l31 = lane & 31, g = lane >> 5;

  const unsigned short* xrow =
      ws16 + XH + (((size_t)(b*4096 + n0 + w*32 + l31)) << 8) + g*8;
  const unsigned short* wbase = ws16 + WH + (size_t)p*32768 + g*8;

  f32x16 acc[4];
  #pragma unroll
  for (int ot = 0; ot < 4; ++ot) acc[ot] = zero16();

  if (p < 2) {
    #pragma unroll
    for (int kt = 0; kt < 16; ++kt) {
      half8 xf = *(const half8*)(xrow + kt*16);
      #pragma unroll
      for (int ot = 0; ot < 4; ++ot) {
        half8 wf = *(const half8*)(wbase + (((size_t)(ot*32 + l31)) << 8) + kt*16);
        acc[ot] = mfmaf16(xf, wf, acc[ot]);   // D[n][o]
      }
    }
    const float* bias = p ? pb : tb;
    unsigned short* outb =
        ws16 + (p ? VT : KT) + (((size_t)(b*4096 + n0 + w*32)) << 7);
    #pragma unroll
    for (int ot = 0; ot < 4; ++ot) {
      float bv = bias[ot*32 + l31];
      #pragma unroll
      for (int r = 0; r < 16; ++r) {
        int row = (r & 3) + 8*(r >> 2) + 4*g;
        outb[(((size_t)row) << 7) + ot*32 + l31] = f2h(acc[ot][r] + bv);
      }
    }
  } else {
    #pragma unroll
    for (int kt = 0; kt < 16; ++kt) {
      half8 xf = *(const half8*)(xrow + kt*16);
      #pragma unroll
      for (int ot = 0; ot < 4; ++ot) {
        half8 wf = *(const half8*)(wbase + (((size_t)(ot*32 + l31)) << 8) + kt*16);
        acc[ot] = mfmaf16(wf, xf, acc[ot]);   // D[o][n]
      }
    }
    unsigned short* outb = ws16 + QT + (((size_t)(b*128)) << 12) + n0 + w*32 + l31;
    #pragma unroll
    for (int ot = 0; ot < 4; ++ot) {
      #pragma unroll
      for (int r = 0; r < 16; ++r) {
        int row = (r & 3) + 8*(r >> 2) + 4*g;
        int o = ot*32 + row;
        outb[((size_t)o) << 12] = f2h(acc[ot][r] + gb[o]);
      }
    }
  }
}

// ---------------------------------------------------------------------------
// Kernel 2: flash attention, fp16 MFMA, swapped QK^T (lane-local softmax rows).
// 4 waves x 32 rows = 128 rows/block; m-split x4. Grid 512 = 2 blocks/CU.
// LDS: double-buffered [V 16K | Q 16K] = 64 KB.
// ---------------------------------------------------------------------------
__device__ __forceinline__ void stage_load(const unsigned short* __restrict__ ws16,
                                           int b, int m0_, int tid, uN4* sv) {
  const unsigned short* Vt = ws16 + VT;
  const unsigned short* Qh = ws16 + QT;
  #pragma unroll
  for (int k = 0; k < 4; ++k) {
    int i = tid + (k << 8); int m = i >> 4, oc = i & 15;
    sv[k] = *(const uN4*)(Vt + (((size_t)(b*4096 + m0_ + m)) << 7) + oc*8);
  }
  #pragma unroll
  for (int k = 0; k < 4; ++k) {
    int j = tid + (k << 8); int o = j >> 3, mc = j & 7;
    sv[4+k] = *(const uN4*)(Qh + (((size_t)(b*128 + o)) << 12) + m0_ + mc*8);
  }
}
__device__ __forceinline__ void stage_write(unsigned char* dst, int tid, const uN4* sv) {
  #pragma unroll
  for (int k = 0; k < 4; ++k) {
    int i = tid + (k << 8); int m = i >> 4, oc = i & 15;
    *(uN4*)(dst + m*256 + ((oc*16) ^ ((m & 15)*16))) = sv[k];
  }
  #pragma unroll
  for (int k = 0; k < 4; ++k) {
    int j = tid + (k << 8); int o = j >> 3, mc = j & 7;
    *(uN4*)(dst + 16384 + o*128 + ((mc*16) ^ ((o & 7)*16))) = sv[4+k];
  }
}

__global__ __launch_bounds__(256, 2)
void attn_kernel(unsigned short* __restrict__ ws16,
                 float* __restrict__ Mst, float* __restrict__ Lst) {
  const int L  = blockIdx.x;            // 512
  const int b  = L & 3;
  const int mh = (L >> 2) & 3;
  const int rb = L >> 4;
  const int r0 = rb * 128;
  const int mbase = mh * 1024;
  constexpr int NT = 16;

  const int tid  = threadIdx.x;
  const int w    = tid >> 6;
  const int lane = tid & 63;
  const int l31  = lane & 31;
  const int g    = lane >> 5;

  __shared__ __align__(16) unsigned char smem[65536];

  const int nrow = r0 + w*32 + l31;
  half8 kh[8];
  {
    const unsigned short* Kt = ws16 + KT + (((size_t)(b*4096 + nrow)) << 7);
    #pragma unroll
    for (int kt = 0; kt < 8; ++kt)
      kh[kt] = *(const half8*)(Kt + kt*16 + g*8);
  }

  f32x16 acc[4];
  #pragma unroll
  for (int ot = 0; ot < 4; ++ot) acc[ot] = zero16();
  float mreg = -INFINITY, lreg = 0.0f;

  uN4 sv[8];
  stage_load(ws16, b, mbase, tid, sv);
  stage_write(smem, tid, sv);
  __syncthreads();

  for (int t = 0; t < NT; ++t) {
    unsigned char* buf  = smem + ((t & 1) << 15);
    unsigned char* nbuf = smem + (((t & 1) ^ 1) << 15);
    if (t + 1 < NT) stage_load(ws16, b, mbase + (t+1)*64, tid, sv);

    f32x16 c0 = zero16(), c1 = zero16();
    __builtin_amdgcn_s_setprio(1);
    #pragma unroll
    for (int kt = 0; kt < 8; ++kt) {
      const int ob = (kt*32 + g*16) ^ ((l31 & 15)*16);
      half8 v0 = *(const half8*)(buf + l31*256 + ob);
      half8 v1 = *(const half8*)(buf + (32 + l31)*256 + ob);
      c0 = mfmaf16(v0, kh[kt], c0);
      c1 = mfmaf16(v1, kh[kt], c1);
    }
    __builtin_amdgcn_s_setprio(0);

    float tm = fmaxf(c0[0], c1[0]);
    #pragma unroll
    for (int r = 1; r < 16; ++r) tm = fmaxf(tm, fmaxf(c0[r], c1[r]));
    tm = fmaxf(tm, __shfl_xor(tm, 32));

    float f = 1.0f;
    if (__any(tm > mreg + 8.0f)) {        // T13 defer-max
      float mn = fmaxf(mreg, tm);
      f = __expf(mreg - mn);
      mreg = mn;
      #pragma unroll
      for (int r = 0; r < 16; ++r) {
        const int nl = (r & 3) + 8*(r >> 2) + 4*g;
        float fr = __shfl(f, nl);
        acc[0][r] *= fr; acc[1][r] *= fr; acc[2][r] *= fr; acc[3][r] *= fr;
      }
    }
    float ts = 0.0f;
    #pragma unroll
    for (int r = 0; r < 16; ++r) { c0[r] = __expf(c0[r] - mreg); ts += c0[r]; }
    #pragma unroll
    for (int r = 0; r < 16; ++r) { c1[r] = __expf(c1[r] - mreg); ts += c1[r]; }
    ts += __shfl_xor(ts, 32);
    lreg = lreg * f + ts;

    half8 pfr[4];
    pfr[0] = build_pfrag(c0[0],c0[1],c0[2],c0[3],c0[4],c0[5],c0[6],c0[7], g);
    pfr[1] = build_pfrag(c0[8],c0[9],c0[10],c0[11],c0[12],c0[13],c0[14],c0[15], g);
    pfr[2] = build_pfrag(c1[0],c1[1],c1[2],c1[3],c1[4],c1[5],c1[6],c1[7], g);
    pfr[3] = build_pfrag(c1[8],c1[9],c1[10],c1[11],c1[12],c1[13],c1[14],c1[15], g);

    __builtin_amdgcn_s_setprio(1);
    #pragma unroll
    for (int kt2 = 0; kt2 < 4; ++kt2) {
      const int qo = kt2*32 + g*16;
      #pragma unroll
      for (int ot = 0; ot < 4; ++ot) {
        const int o_ = ot*32 + l31;
        half8 qf = *(const half8*)(buf + 16384 + o_*128 + (qo ^ ((o_ & 7)*16)));
        acc[ot] = mfmaf16(pfr[kt2], qf, acc[ot]);
      }
    }
    __builtin_amdgcn_s_setprio(0);

    if (t + 1 < NT) stage_write(nbuf, tid, sv);
    __syncthreads();
  }

  // epilogue: normalized fp16 partial -> OB[mh][b][n][o] (coalesced over o)
  unsigned short* Ob = ws16 + OB + (size_t)mh*OSZ + (((size_t)(b*4096)) << 7);
  const float linv_own = 1.0f / lreg;
  #pragma unroll
  for (int r = 0; r < 16; ++r) {
    const int nl = (r & 3) + 8*(r >> 2) + 4*g;
    const float linv = __shfl(linv_own, nl);
    const size_t nb = ((size_t)(r0 + w*32 + nl)) << 7;
    #pragma unroll
    for (int ot = 0; ot < 4; ++ot) {
      const int o_ = ot*32 + l31;
      Ob[nb + o_] = f2h(acc[ot][r] * linv);
    }
  }
  if (lane < 32) {
    const int n_ = r0 + w*32 + l31;
    Mst[((mh*4 + b) << 12) + n_] = mreg;
    Lst[((mh*4 + b) << 12) + n_] = lreg;
  }
}

// ---------------------------------------------------------------------------
// Kernel 3: out projection via MFMA with fused 4-partial merge (pk_fma_f16).
// Grid 256: b(4) x nt(64: 64 n). Block: 256c x 64n. Wave: (w>>1) c-half,
// (w&1) n-sub. D[c][n] + w_b + x -> out (coalesced fp32 over n).
// ---------------------------------------------------------------------------
__global__ __launch_bounds__(256)
void out_kernel(const float* __restrict__ x, const float* __restrict__ wb,
                const unsigned short* __restrict__ ws16,
                const float* __restrict__ Mst, const float* __restrict__ Lst,
                float* __restrict__ out) {
  const int L = blockIdx.x;            // 256
  const int b = L & 3, nt = L >> 2;
  const int n0 = nt * 64;
  const int tid = threadIdx.x, w = tid >> 6, lane = tid & 63;
  const int l31 = lane & 31, g = lane >> 5;
  const int nsub = w & 1, chalf = w >> 1;

  __shared__ float cs[4][64];
  if (tid < 64) {
    const int n_ = n0 + tid;
    float m0 = Mst[((0*4+b) << 12) + n_], l0 = Lst[((0*4+b) << 12) + n_];
    float m1 = Mst[((1*4+b) << 12) + n_], l1 = Lst[((1*4+b) << 12) + n_];
    float m2 = Mst[((2*4+b) << 12) + n_], l2 = Lst[((2*4+b) << 12) + n_];
    float m3 = Mst[((3*4+b) << 12) + n_], l3 = Lst[((3*4+b) << 12) + n_];
    float M = fmaxf(fmaxf(m0, m1), fmaxf(m2, m3));
    float w0 = l0 * __expf(m0 - M);
    float w1 = l1 * __expf(m1 - M);
    float w2 = l2 * __expf(m2 - M);
    float w3 = l3 * __expf(m3 - M);
    float inv = 1.0f / (w0 + w1 + w2 + w3);
    cs[0][tid] = w0*inv; cs[1][tid] = w1*inv; cs[2][tid] = w2*inv; cs[3][tid] = w3*inv;
  }
  __syncthreads();

  const int n_lane = n0 + nsub*32 + l31;
  unsigned csh[4];
  #pragma unroll
  for (int p = 0; p < 4; ++p) {
    float c = cs[p][nsub*32 + l31];
    csh[p] = pkf(c, c);
  }

  f32x16 acc[4];
  #pragma unroll
  for (int ct = 0; ct < 4; ++ct) acc[ct] = zero16();

  const unsigned short* ob = ws16 + OB + (((size_t)(b*4096 + n_lane)) << 7) + g*8;
  const unsigned short* wrow = ws16 + WOH + g*8;

  #pragma unroll
  for (int kt = 0; kt < 8; ++kt) {
    uN4 u0 = *(const uN4*)(ob + kt*16);
    uN4 u1 = *(const uN4*)(ob + OSZ + kt*16);
    uN4 u2 = *(const uN4*)(ob + 2*OSZ + kt*16);
    uN4 u3 = *(const uN4*)(ob + 3*OSZ + kt*16);
    union { uN4 u; half8 h; } m;
    #pragma unroll
    for (int i = 0; i < 4; ++i)
      m.u[i] = pkfma(u0[i], csh[0],
               pkfma(u1[i], csh[1],
               pkfma(u2[i], csh[2], pkmul(u3[i], csh[3]))));
    #pragma unroll
    for (int ct = 0; ct < 4; ++ct) {
      half8 wf = *(const half8*)(wrow + (((size_t)((chalf*4 + ct)*32 + l31)) << 7) + kt*16);
      acc[ct] = mfmaf16(wf, m.h, acc[ct]);   // D[c][n]
    }
  }

  #pragma unroll
  for (int ct = 0; ct < 4; ++ct) {
    #pragma unroll
    for (int r = 0; r < 16; ++r) {
      const int c = (chalf*4 + ct)*32 + (r & 3) + 8*(r >> 2) + 4*g;
      const size_t off = ((size_t)(b*256 + c) << 12) + n_lane;
      out[off] = acc[ct][r] + wb[c] + x[off];
    }
  }
}

extern "C" void kernel_launch(void* const* d_in, const int* in_sizes, int n_in,
                              void* d_out, int out_size, void* d_ws, size_t ws_size,
                              hipStream_t stream) {
  const float* x  = (const float*)d_in[0];
  const float* tw = (const float*)d_in[1];
  const float* tb = (const float*)d_in[2];
  const float* pw = (const float*)d_in[3];
  const float* pb = (const float*)d_in[4];
  const float* gw = (const float*)d_in[5];
  const float* gb = (const float*)d_in[6];
  const float* ww = (const float*)d_in[7];
  const float* wbb= (const float*)d_in[8];

  unsigned short* ws16 = (unsigned short*)d_ws;
  float* Mst = (float*)((char*)d_ws + STAT_BYTE);
  float* Lst = Mst + 16*4096;
  float* out = (float*)d_out;

  if (ws_size < 33554432u) return;   // >= 32 MB (proven available in round 1)

  prep_kernel<<<1024, 256, 0, stream>>>(x, tw, pw, gw, ww, ws16);
  proj_kernel<<<384, 256, 0, stream>>>(tb, pb, gb, ws16);
  attn_kernel<<<512, 256, 0, stream>>>(ws16, Mst, Lst);
  out_kernel<<<256, 256, 0, stream>>>(x, wbb, ws16, Mst, Lst, out);
}

// Round 6
// 91.167 us; speedup vs baseline: 8.4241x; 1.0474x over previous
//
#include <hip/hip_runtime.h>
#include <hip/hip_bf16.h>
#include <math.h>

typedef float  float4v __attribute__((ext_vector_type(4)));
typedef float  f32x16  __attribute__((ext_vector_type(16)));
typedef _Float16 half8  __attribute__((ext_vector_type(8)));
typedef _Float16 h2v    __attribute__((ext_vector_type(2)));
typedef __fp16  fp16x2 __attribute__((ext_vector_type(2)));
typedef unsigned int   uN4 __attribute__((ext_vector_type(4)));
typedef unsigned int   uint2v __attribute__((ext_vector_type(2)));
typedef unsigned short us4 __attribute__((ext_vector_type(4)));

constexpr int Cc = 256;    // C_IN
constexpr int Ci = 128;    // C_INT
constexpr int Nn = 4096;   // H*W
constexpr float LOG2E = 1.4426950408889634f;

// ws layout (ushort units). All fp16 unless noted.
constexpr size_t KT  = 0;          // K [b][n][o]   (4 MB)  — log2e-scaled
constexpr size_t VT  = 2097152;    // V [b][m][o]   (4 MB)
constexpr size_t QT  = 4194304;    // Q [b][o][n]   (4 MB)
constexpr size_t OB  = 6291456;    // O partials [mh][b][n][o], 4 x 4 MB
constexpr size_t OSZ = 2097152;
constexpr size_t XH  = 6291456;    // x^T [b][n][c] fp16 (8 MB) — ALIASES OB[0..1]
constexpr size_t STAT_BYTE = 29360128;  // Mst[16][4096], Lst[16][4096] f32
constexpr size_t WH  = 14942208;   // stacked weights fp16 [384][256]
constexpr size_t WOH = 15040512;   // w_w fp16 [256][128]

__device__ __forceinline__ f32x16 zero16() {
  f32x16 z;
  #pragma unroll
  for (int r = 0; r < 16; ++r) z[r] = 0.0f;
  return z;
}
__device__ __forceinline__ unsigned pkf(float x, float y) {
  union { fp16x2 h; unsigned u; } c;
  c.h = __builtin_amdgcn_cvt_pkrtz(x, y);
  return c.u;
}
__device__ __forceinline__ f32x16 mfmaf16(half8 a, half8 b, f32x16 c) {
  return __builtin_amdgcn_mfma_f32_32x32x16_f16(a, b, c, 0, 0, 0);
}
__device__ __forceinline__ float h2f(unsigned short u) {
  union { unsigned short u; _Float16 h; } c; c.u = u; return (float)c.h;
}
__device__ __forceinline__ unsigned short f2h(float x) {
  union { _Float16 h; unsigned short u; } c; c.h = (_Float16)x; return c.u;
}
__device__ __forceinline__ unsigned pkfma(unsigned a, unsigned b, unsigned c) {
  union { unsigned u; h2v h; } A, B, C, R;
  A.u = a; B.u = b; C.u = c;
  R.h = A.h * B.h + C.h;
  return R.u;
}
__device__ __forceinline__ unsigned pkmul(unsigned a, unsigned b) {
  union { unsigned u; h2v h; } A, B, R;
  A.u = a; B.u = b;
  R.h = A.h * B.h;
  return R.u;
}
// native 2^x (logits are pre-scaled to log2 domain). s_nop covers the
// trans->VALU use hazard the compiler can't see inside asm.
__device__ __forceinline__ float ex2(float x) {
  float r;
  asm volatile("v_exp_f32 %0, %1\n\ts_nop 0" : "=v"(r) : "v"(x));
  return r;
}
// async global->LDS, 16B per lane. dest must be wave-uniform base + lane*16.
__device__ __forceinline__ void gload16(const unsigned short* src, unsigned char* lds) {
  __builtin_amdgcn_global_load_lds(
      (const __attribute__((address_space(1))) unsigned int*)src,
      (__attribute__((address_space(3))) unsigned int*)lds,
      16, 0, 0);
}

// PV A-fragment from this lane's 8 P-values via permlane32_swap (T12).
// rA = swap(a0,b0): rA.x = [a0.lo | b0.lo], rA.y = [a0.hi | b0.hi]
// -> frag words are {rA.x, rB.x, rA.y, rB.y} for BOTH halves, no selects.
__device__ __forceinline__ half8 pfrag2(float p0, float p1, float p2, float p3,
                                        float p4, float p5, float p6, float p7) {
  unsigned a0 = pkf(p0, p1), a1 = pkf(p2, p3);
  unsigned b0 = pkf(p4, p5), b1 = pkf(p6, p7);
  uint2v rA = __builtin_amdgcn_permlane32_swap(a0, b0, false, false);
  uint2v rB = __builtin_amdgcn_permlane32_swap(a1, b1, false, false);
  union { unsigned u[4]; half8 h; } r;
  r.u[0] = rA.x; r.u[1] = rB.x; r.u[2] = rA.y; r.u[3] = rB.y;
  return r.h;
}

// ---------------------------------------------------------------------------
// Kernel 0: prep — x[b][c][n] f32 -> xT[b][n][c] fp16 (64x64 LDS transpose);
// blocks 0..127 also convert weights (theta scaled by log2e).
// ---------------------------------------------------------------------------
__global__ __launch_bounds__(256)
void prep_kernel(const float* __restrict__ x,
                 const float* __restrict__ tw, const float* __restrict__ pw,
                 const float* __restrict__ gw, const float* __restrict__ ww,
                 unsigned short* __restrict__ ws16) {
  const int L = blockIdx.x;            // 1024 = b(4) x nt(64) x ct(4)
  const int b = L >> 8, rem = L & 255, nt = rem >> 2, ct = rem & 3;
  const int n0 = nt * 64, c0 = ct * 64;
  __shared__ unsigned short T[64][68];
  const int tid = threadIdx.x;
  const int tn = (tid & 15) * 4, tc = tid >> 4;

  #pragma unroll
  for (int it = 0; it < 4; ++it) {
    const int c = it*16 + tc;
    float4v v = *(const float4v*)(x + (((size_t)(b*256 + c0 + c)) << 12) + n0 + tn);
    #pragma unroll
    for (int k = 0; k < 4; ++k) T[tn + k][c] = f2h(v[k]);
  }

  if (L < 128) {    // weight conversion fold
    int i = L*1024 + tid*4;
    const float* src; unsigned short* dst; float sc = 1.0f;
    if (i < 32768)      { src = tw + i;           dst = ws16 + WH + i; sc = LOG2E; }
    else if (i < 65536) { src = pw + (i - 32768); dst = ws16 + WH + i; }
    else if (i < 98304) { src = gw + (i - 65536); dst = ws16 + WH + i; }
    else                { src = ww + (i - 98304); dst = ws16 + WOH + (i - 98304); }
    float4v v = *(const float4v*)src;
    us4 o;
    #pragma unroll
    for (int k = 0; k < 4; ++k) o[k] = f2h(v[k] * sc);
    *(us4*)dst = o;
  }
  __syncthreads();

  const int wn = tid >> 4, wc = (tid & 15) * 4;
  #pragma unroll
  for (int it = 0; it < 4; ++it) {
    const int n = it*16 + wn;
    us4 o;
    #pragma unroll
    for (int k = 0; k < 4; ++k) o[k] = T[n][wc + k];
    *(us4*)(ws16 + XH + (((size_t)(b*4096 + n0 + n)) << 8) + c0 + wc) = o;
  }
}

// ---------------------------------------------------------------------------
// Kernel 1: projections via MFMA, no LDS. 384 blocks: p(3) x b(4) x nt(32).
// ---------------------------------------------------------------------------
__global__ __launch_bounds__(256)
void proj_kernel(const float* __restrict__ tb, const float* __restrict__ pb,
                 const float* __restrict__ gb, unsigned short* __restrict__ ws16) {
  const int L = blockIdx.x;          // 384
  const int p = L >> 7;              // 0=K,1=V,2=Q
  const int rem = L & 127;
  const int b = rem & 3, nt = rem >> 2;
  const int n0 = nt * 128;
  const int tid = threadIdx.x, w = tid >> 6, lane = tid & 63;
  const int l31 = lane & 31, g = lane >> 5;

  const unsigned short* xrow =
      ws16 + XH + (((size_t)(b*4096 + n0 + w*32 + l31)) << 8) + g*8;
  const unsigned short* wbase = ws16 + WH + (size_t)p*32768 + g*8;

  f32x16 acc[4];
  #pragma unroll
  for (int ot = 0; ot < 4; ++ot) acc[ot] = zero16();

  if (p < 2) {
    #pragma unroll
    for (int kt = 0; kt < 16; ++kt) {
      half8 xf = *(const half8*)(xrow + kt*16);
      #pragma unroll
      for (int ot = 0; ot < 4; ++ot) {
        half8 wf = *(const half8*)(wbase + (((size_t)(ot*32 + l31)) << 8) + kt*16);
        acc[ot] = mfmaf16(xf, wf, acc[ot]);   // D[n][o]
      }
    }
    const float* bias = p ? pb : tb;
    const float bscale = p ? 1.0f : LOG2E;
    unsigned short* outb =
        ws16 + (p ? VT : KT) + (((size_t)(b*4096 + n0 + w*32)) << 7);
    #pragma unroll
    for (int ot = 0; ot < 4; ++ot) {
      float bv = bias[ot*32 + l31] * bscale;
      #pragma unroll
      for (int r = 0; r < 16; ++r) {
        int row = (r & 3) + 8*(r >> 2) + 4*g;
        outb[(((size_t)row) << 7) + ot*32 + l31] = f2h(acc[ot][r] + bv);
      }
    }
  } else {
    #pragma unroll
    for (int kt = 0; kt < 16; ++kt) {
      half8 xf = *(const half8*)(xrow + kt*16);
      #pragma unroll
      for (int ot = 0; ot < 4; ++ot) {
        half8 wf = *(const half8*)(wbase + (((size_t)(ot*32 + l31)) << 8) + kt*16);
        acc[ot] = mfmaf16(wf, xf, acc[ot]);   // D[o][n]
      }
    }
    unsigned short* outb = ws16 + QT + (((size_t)(b*128)) << 12) + n0 + w*32 + l31;
    #pragma unroll
    for (int ot = 0; ot < 4; ++ot) {
      #pragma unroll
      for (int r = 0; r < 16; ++r) {
        int row = (r & 3) + 8*(r >> 2) + 4*g;
        int o = ot*32 + row;
        outb[((size_t)o) << 12] = f2h(acc[ot][r] + gb[o]);
      }
    }
  }
}

// ---------------------------------------------------------------------------
// Kernel 2: flash attention, fp16 MFMA, swapped QK^T, exp2-domain softmax,
// global_load_lds DMA staging (linear dest + pre-swizzled source).
// 4 waves x 32 rows; m-split x4. Grid 512 = 2 blocks/CU. LDS 64 KB dbuf.
// ---------------------------------------------------------------------------
__device__ __forceinline__ void stage_dma(const unsigned short* __restrict__ ws16,
                                          int b, int m0_, int tid, int w,
                                          unsigned char* nbuf) {
  const unsigned short* Vt = ws16 + VT;
  const unsigned short* Qh = ws16 + QT;
  // V tile [m 64][o 128] fp16, swizzle (oc*16)^((m&15)*16) folded into SOURCE
  #pragma unroll
  for (int k = 0; k < 4; ++k) {
    int e = tid + (k << 8); int m = e >> 4, oc = e & 15;
    const unsigned short* src =
        Vt + (((size_t)(b*4096 + m0_ + m)) << 7) + ((oc*8) ^ ((m & 15)*8));
    gload16(src, nbuf + ((k << 8) + (w << 6))*16);
  }
  // Q tile [o 128][m 64] fp16, swizzle (mc*16)^((o&7)*16) folded into SOURCE
  #pragma unroll
  for (int k = 0; k < 4; ++k) {
    int e = tid + (k << 8); int o = e >> 3, mc = e & 7;
    const unsigned short* src =
        Qh + (((size_t)(b*128 + o)) << 12) + m0_ + ((mc*8) ^ ((o & 7)*8));
    gload16(src, nbuf + 16384 + ((k << 8) + (w << 6))*16);
  }
}

__global__ __launch_bounds__(256, 2)
void attn_kernel(unsigned short* __restrict__ ws16,
                 float* __restrict__ Mst, float* __restrict__ Lst) {
  const int L  = blockIdx.x;            // 512
  const int b  = L & 3;
  const int mh = (L >> 2) & 3;
  const int rb = L >> 4;
  const int r0 = rb * 128;
  const int mbase = mh * 1024;
  constexpr int NT = 16;

  const int tid  = threadIdx.x;
  const int w    = tid >> 6;
  const int lane = tid & 63;
  const int l31  = lane & 31;
  const int g    = lane >> 5;

  __shared__ __align__(16) unsigned char smem[65536];

  const int nrow = r0 + w*32 + l31;
  half8 kh[8];
  {
    const unsigned short* Kt = ws16 + KT + (((size_t)(b*4096 + nrow)) << 7);
    #pragma unroll
    for (int kt = 0; kt < 8; ++kt)
      kh[kt] = *(const half8*)(Kt + kt*16 + g*8);
  }

  f32x16 acc[4];
  #pragma unroll
  for (int ot = 0; ot < 4; ++ot) acc[ot] = zero16();
  float mreg = -INFINITY, lreg = 0.0f;

  stage_dma(ws16, b, mbase, tid, w, smem);
  __syncthreads();          // vmcnt(0) drained by compiler before barrier

  for (int t = 0; t < NT; ++t) {
    unsigned char* buf  = smem + ((t & 1) << 15);
    unsigned char* nbuf = smem + (((t & 1) ^ 1) << 15);
    if (t + 1 < NT) stage_dma(ws16, b, mbase + (t+1)*64, tid, w, nbuf);

    // ---- logits (log2 domain): S^T = V * K' ----
    f32x16 c0 = zero16(), c1 = zero16();
    __builtin_amdgcn_s_setprio(1);
    #pragma unroll
    for (int kt = 0; kt < 8; ++kt) {
      const int ob = (kt*32 + g*16) ^ ((l31 & 15)*16);
      half8 v0 = *(const half8*)(buf + l31*256 + ob);
      half8 v1 = *(const half8*)(buf + (32 + l31)*256 + ob);
      c0 = mfmaf16(v0, kh[kt], c0);
      c1 = mfmaf16(v1, kh[kt], c1);
    }
    __builtin_amdgcn_s_setprio(0);

    // ---- softmax: lane owns row n = l31 (both halves), tree reductions ----
    float mx[8];
    #pragma unroll
    for (int i = 0; i < 8; ++i)
      mx[i] = fmaxf(fmaxf(c0[i], c0[i+8]), fmaxf(c1[i], c1[i+8]));
    #pragma unroll
    for (int i = 0; i < 4; ++i) mx[i] = fmaxf(mx[i], mx[i+4]);
    float tm = fmaxf(fmaxf(mx[0], mx[1]), fmaxf(mx[2], mx[3]));
    tm = fmaxf(tm, __shfl_xor(tm, 32));

    float f = 1.0f;
    if (__any(tm > mreg + 11.0f)) {       // T13 defer-max (log2 units)
      float mn = fmaxf(mreg, tm);
      f = ex2(mreg - mn);
      mreg = mn;
      #pragma unroll
      for (int r = 0; r < 16; ++r) {
        const int nl = (r & 3) + 8*(r >> 2) + 4*g;
        float fr = __shfl(f, nl);
        acc[0][r] *= fr; acc[1][r] *= fr; acc[2][r] *= fr; acc[3][r] *= fr;
      }
    }
    #pragma unroll
    for (int r = 0; r < 16; ++r) { c0[r] = ex2(c0[r] - mreg); }
    #pragma unroll
    for (int r = 0; r < 16; ++r) { c1[r] = ex2(c1[r] - mreg); }
    float sm[8];
    #pragma unroll
    for (int i = 0; i < 8; ++i) sm[i] = (c0[i] + c0[i+8]) + (c1[i] + c1[i+8]);
    #pragma unroll
    for (int i = 0; i < 4; ++i) sm[i] += sm[i+4];
    float ts = (sm[0] + sm[1]) + (sm[2] + sm[3]);
    ts += __shfl_xor(ts, 32);
    lreg = lreg * f + ts;

    // ---- P -> PV A-fragments (permlane32_swap, no LDS / no selects) ----
    half8 pfr[4];
    pfr[0] = pfrag2(c0[0],c0[1],c0[2],c0[3],c0[4],c0[5],c0[6],c0[7]);
    pfr[1] = pfrag2(c0[8],c0[9],c0[10],c0[11],c0[12],c0[13],c0[14],c0[15]);
    pfr[2] = pfrag2(c1[0],c1[1],c1[2],c1[3],c1[4],c1[5],c1[6],c1[7]);
    pfr[3] = pfrag2(c1[8],c1[9],c1[10],c1[11],c1[12],c1[13],c1[14],c1[15]);

    // ---- PV ----
    __builtin_amdgcn_s_setprio(1);
    #pragma unroll
    for (int kt2 = 0; kt2 < 4; ++kt2) {
      const int qo = kt2*32 + g*16;
      #pragma unroll
      for (int ot = 0; ot < 4; ++ot) {
        const int o_ = ot*32 + l31;
        half8 qf = *(const half8*)(buf + 16384 + o_*128 + (qo ^ ((o_ & 7)*16)));
        acc[ot] = mfmaf16(pfr[kt2], qf, acc[ot]);
      }
    }
    __builtin_amdgcn_s_setprio(0);

    __syncthreads();
  }

  // epilogue: normalized fp16 partial -> OB[mh][b][n][o]
  unsigned short* Ob = ws16 + OB + (size_t)mh*OSZ + (((size_t)(b*4096)) << 7);
  const float linv_own = 1.0f / lreg;
  #pragma unroll
  for (int r = 0; r < 16; ++r) {
    const int nl = (r & 3) + 8*(r >> 2) + 4*g;
    const float linv = __shfl(linv_own, nl);
    const size_t nb = ((size_t)(r0 + w*32 + nl)) << 7;
    #pragma unroll
    for (int ot = 0; ot < 4; ++ot) {
      const int o_ = ot*32 + l31;
      Ob[nb + o_] = f2h(acc[ot][r] * linv);
    }
  }
  if (lane < 32) {
    const int n_ = r0 + w*32 + l31;
    Mst[((mh*4 + b) << 12) + n_] = mreg;   // log2 domain
    Lst[((mh*4 + b) << 12) + n_] = lreg;
  }
}

// ---------------------------------------------------------------------------
// Kernel 3: out projection via MFMA with fused 4-partial merge (pk_fma_f16).
// ---------------------------------------------------------------------------
__global__ __launch_bounds__(256)
void out_kernel(const float* __restrict__ x, const float* __restrict__ wb,
                const unsigned short* __restrict__ ws16,
                const float* __restrict__ Mst, const float* __restrict__ Lst,
                float* __restrict__ out) {
  const int L = blockIdx.x;            // 256
  const int b = L & 3, nt = L >> 2;
  const int n0 = nt * 64;
  const int tid = threadIdx.x, w = tid >> 6, lane = tid & 63;
  const int l31 = lane & 31, g = lane >> 5;
  const int nsub = w & 1, chalf = w >> 1;

  __shared__ float cs[4][64];
  if (tid < 64) {
    const int n_ = n0 + tid;
    float m0 = Mst[((0*4+b) << 12) + n_], l0 = Lst[((0*4+b) << 12) + n_];
    float m1 = Mst[((1*4+b) << 12) + n_], l1 = Lst[((1*4+b) << 12) + n_];
    float m2 = Mst[((2*4+b) << 12) + n_], l2 = Lst[((2*4+b) << 12) + n_];
    float m3 = Mst[((3*4+b) << 12) + n_], l3 = Lst[((3*4+b) << 12) + n_];
    float M = fmaxf(fmaxf(m0, m1), fmaxf(m2, m3));
    float w0 = l0 * exp2f(m0 - M);       // stats are log2-domain
    float w1 = l1 * exp2f(m1 - M);
    float w2 = l2 * exp2f(m2 - M);
    float w3 = l3 * exp2f(m3 - M);
    float inv = 1.0f / (w0 + w1 + w2 + w3);
    cs[0][tid] = w0*inv; cs[1][tid] = w1*inv; cs[2][tid] = w2*inv; cs[3][tid] = w3*inv;
  }
  __syncthreads();

  const int n_lane = n0 + nsub*32 + l31;
  unsigned csh[4];
  #pragma unroll
  for (int p = 0; p < 4; ++p) {
    float c = cs[p][nsub*32 + l31];
    csh[p] = pkf(c, c);
  }

  f32x16 acc[4];
  #pragma unroll
  for (int ct = 0; ct < 4; ++ct) acc[ct] = zero16();

  const unsigned short* ob = ws16 + OB + (((size_t)(b*4096 + n_lane)) << 7) + g*8;
  const unsigned short* wrow = ws16 + WOH + g*8;

  #pragma unroll
  for (int kt = 0; kt < 8; ++kt) {
    uN4 u0 = *(const uN4*)(ob + kt*16);
    uN4 u1 = *(const uN4*)(ob + OSZ + kt*16);
    uN4 u2 = *(const uN4*)(ob + 2*OSZ + kt*16);
    uN4 u3 = *(const uN4*)(ob + 3*OSZ + kt*16);
    union { uN4 u; half8 h; } m;
    #pragma unroll
    for (int i = 0; i < 4; ++i)
      m.u[i] = pkfma(u0[i], csh[0],
               pkfma(u1[i], csh[1],
               pkfma(u2[i], csh[2], pkmul(u3[i], csh[3]))));
    #pragma unroll
    for (int ct = 0; ct < 4; ++ct) {
      half8 wf = *(const half8*)(wrow + (((size_t)((chalf*4 + ct)*32 + l31)) << 7) + kt*16);
      acc[ct] = mfmaf16(wf, m.h, acc[ct]);   // D[c][n]
    }
  }

  #pragma unroll
  for (int ct = 0; ct < 4; ++ct) {
    #pragma unroll
    for (int r = 0; r < 16; ++r) {
      const int c = (chalf*4 + ct)*32 + (r & 3) + 8*(r >> 2) + 4*g;
      const size_t off = ((size_t)(b*256 + c) << 12) + n_lane;
      out[off] = acc[ct][r] + wb[c] + x[off];
    }
  }
}

extern "C" void kernel_launch(void* const* d_in, const int* in_sizes, int n_in,
                              void* d_out, int out_size, void* d_ws, size_t ws_size,
                              hipStream_t stream) {
  const float* x  = (const float*)d_in[0];
  const float* tw = (const float*)d_in[1];
  const float* tb = (const float*)d_in[2];
  const float* pw = (const float*)d_in[3];
  const float* pb = (const float*)d_in[4];
  const float* gw = (const float*)d_in[5];
  const float* gb = (const float*)d_in[6];
  const float* ww = (const float*)d_in[7];
  const float* wbb= (const float*)d_in[8];

  unsigned short* ws16 = (unsigned short*)d_ws;
  float* Mst = (float*)((char*)d_ws + STAT_BYTE);
  float* Lst = Mst + 16*4096;
  float* out = (float*)d_out;

  if (ws_size < 33554432u) return;

  prep_kernel<<<1024, 256, 0, stream>>>(x, tw, pw, gw, ww, ws16);
  proj_kernel<<<384, 256, 0, stream>>>(tb, pb, gb, ws16);
  attn_kernel<<<512, 256, 0, stream>>>(ws16, Mst, Lst);
  out_kernel<<<256, 256, 0, stream>>>(x, wbb, ws16, Mst, Lst, out);
}